// Round 1
// 292.774 us; speedup vs baseline: 1.1135x; 1.1135x over previous
//
#include <hip/hip_runtime.h>
#include <cmath>

// GCN 2-layer forward on MI355X — round 6: norm factorized into GEMM epilogue
// (dinv pre-scaling kills the per-edge dinv gather + FMA), aggregation kernels
// rebuilt as 2-nodes-per-wave with uint2 (8B/lane) row gathers for 2x MLP.
// Pipeline: bcount -> bscan -> bscatter(packed) -> bbuild ->
//           gemm1_mfma(x@W1 * dinv -> bf16) -> agg128 (pure-add, bias+relu -> bf16 h1) ->
//           gemm2_mfma(h1@W2 * dinv -> bf16) -> agg64+log_softmax fused -> done.

#define THREADS 256
#define BSHIFT 8                      // 256 nodes per bucket
#define MAXB 512                      // >= ceil(N / 256)

__device__ __forceinline__ unsigned short f2bf(float f) {
    union { float f; unsigned u; } v; v.f = f;
    unsigned r = v.u + 0x7FFFu + ((v.u >> 16) & 1u);   // round-nearest-even
    return (unsigned short)(r >> 16);
}
__device__ __forceinline__ float bf_lo(unsigned u) {
    union { unsigned u; float f; } v; v.u = u << 16; return v.f;
}
__device__ __forceinline__ float bf_hi(unsigned u) {
    union { unsigned u; float f; } v; v.u = u & 0xFFFF0000u; return v.f;
}

// ---- bucket count: LDS histogram, flush once per block ----
__global__ __launch_bounds__(256) void k_bcount(const int* __restrict__ dst, int E, int B,
                                                int* __restrict__ bcnt) {
    __shared__ int lc[MAXB];
    for (int i = threadIdx.x; i < MAXB; i += 256) lc[i] = 0;
    __syncthreads();
    for (int e = blockIdx.x * blockDim.x + threadIdx.x; e < E; e += gridDim.x * blockDim.x)
        atomicAdd(&lc[dst[e] >> BSHIFT], 1);
    __syncthreads();
    for (int b = threadIdx.x; b < B; b += 256)
        if (lc[b]) atomicAdd(&bcnt[b], lc[b]);
}

// ---- exclusive scan of bcnt[B] -> boff[B+1], single block of 512 ----
__global__ void k_bscan(const int* __restrict__ bcnt, int B, int* __restrict__ boff) {
    __shared__ int sh[MAXB];
    const int t = threadIdx.x;
    int v = (t < B) ? bcnt[t] : 0;
    sh[t] = v; __syncthreads();
    for (int o = 1; o < MAXB; o <<= 1) {
        int add = (t >= o) ? sh[t - o] : 0;
        __syncthreads();
        sh[t] += add;
        __syncthreads();
    }
    if (t < B) boff[t] = sh[t] - v;
    if (t == B - 1) boff[B] = sh[t];
}

// ---- scatter edges into bucket-contiguous packed records (loc<<24 | src) ----
__global__ __launch_bounds__(256) void k_bscatter(const int* __restrict__ src,
                                                  const int* __restrict__ dst, int E, int B,
                                                  const int* __restrict__ boff,
                                                  int* __restrict__ bfill,
                                                  unsigned* __restrict__ pairs) {
    __shared__ int lc[MAXB];     // per-block bucket count, then per-bucket rank
    __shared__ int lbase[MAXB];  // global reservation base within bucket
    const int tid = threadIdx.x;
    const int e0 = blockIdx.x * 8192;
    for (int i = tid; i < MAXB; i += 256) lc[i] = 0;
    __syncthreads();
#pragma unroll
    for (int k = 0; k < 32; k++) {
        int e = e0 + k * 256 + tid;
        if (e < E) atomicAdd(&lc[dst[e] >> BSHIFT], 1);
    }
    __syncthreads();
    for (int b = tid; b < B; b += 256)
        lbase[b] = lc[b] ? atomicAdd(&bfill[b], lc[b]) : 0;
    __syncthreads();
    for (int i = tid; i < MAXB; i += 256) lc[i] = 0;  // reuse as rank
    __syncthreads();
#pragma unroll
    for (int k = 0; k < 32; k++) {
        int e = e0 + k * 256 + tid;
        if (e < E) {
            int s = src[e], d = dst[e];
            int b = d >> BSHIFT;
            int r = atomicAdd(&lc[b], 1);
            pairs[(size_t)boff[b] + lbase[b] + r] =
                ((unsigned)(d & 255) << 24) | (unsigned)s;   // src < 2^24
        }
    }
}

// ---- per-bucket CSR build: one block per bucket; all scatter is XCD-local ----
__global__ __launch_bounds__(256) void k_bbuild(const unsigned* __restrict__ pairs,
                                                const int* __restrict__ boff, int N,
                                                int* __restrict__ deg,
                                                float* __restrict__ dinv,
                                                int* __restrict__ rowptr,
                                                int* __restrict__ csr_src) {
    __shared__ int ldeg[256], lex[256], lrank[256];
    const int b = blockIdx.x, tid = threadIdx.x;
    const int node0 = b << BSHIFT;
    const int base = boff[b];
    const int cnt_e = boff[b + 1] - base;
    ldeg[tid] = 0;
    __syncthreads();
    for (int e = tid; e < cnt_e; e += 256)
        atomicAdd(&ldeg[pairs[base + e] >> 24], 1);
    __syncthreads();
    int v = ldeg[tid];
    lex[tid] = v; __syncthreads();
    for (int o = 1; o < 256; o <<= 1) {
        int add = (tid >= o) ? lex[tid - o] : 0;
        __syncthreads();
        lex[tid] += add;
        __syncthreads();
    }
    int excl = lex[tid] - v;
    if (node0 + tid < N) {
        deg[node0 + tid] = v;
        dinv[node0 + tid] = rsqrtf((float)(v + 1));
        rowptr[node0 + tid] = base + excl;
    }
    __syncthreads();
    lex[tid] = excl;       // keep exclusive offsets
    lrank[tid] = 0;
    __syncthreads();
    for (int e = tid; e < cnt_e; e += 256) {
        unsigned p = pairs[base + e];
        int loc = p >> 24;
        int r = atomicAdd(&lrank[loc], 1);
        csr_src[base + lex[loc] + r] = (int)(p & 0xFFFFFFu);
    }
}

// Wt1[n][k] = bf16(W1[k][n]) (128x128), Wt2[n][k] = bf16(W2[k][n]) (64x128)
__global__ void k_castW(const float* __restrict__ W1, const float* __restrict__ W2,
                        unsigned short* __restrict__ Wt1, unsigned short* __restrict__ Wt2) {
    int idx = blockIdx.x * blockDim.x + threadIdx.x;
    if (idx < 16384) {
        int n = idx >> 7, k = idx & 127;
        Wt1[idx] = f2bf(W1[k * 128 + n]);
    } else if (idx < 16384 + 8192) {
        int t = idx - 16384;
        int n = t >> 7, k = t & 127;
        Wt2[t] = f2bf(W2[k * 64 + n]);
    }
}

// C[M x NC](bf16) = dinv[row] * (A[M x 128] @ Wt^T), Wt is [NC x 128] bf16.
// The dinv pre-scale factorizes the symmetric GCN norm so the aggregation
// kernels need no per-edge dinv gather / multiply.
typedef __attribute__((ext_vector_type(8))) short bf16x8;
typedef __attribute__((ext_vector_type(4))) float f32x4;

template <int NC, bool A_BF16>
__global__ __launch_bounds__(256) void k_gemm_mfma(const void* __restrict__ Av,
                                                   const unsigned short* __restrict__ Wt,
                                                   const float* __restrict__ dinv,
                                                   unsigned short* __restrict__ Out, int M) {
    constexpr int KP = 136;                 // padded k-stride
    __shared__ __align__(16) short As[64 * KP];
    __shared__ __align__(16) short Bs[NC * KP];
    const int tid = threadIdx.x;
    const int row0 = blockIdx.x * 64;

    if (A_BF16) {
        const unsigned short* A = (const unsigned short*)Av;
#pragma unroll
        for (int q = 0; q < 4; q++) {
            int f = tid + 256 * q;
            int r = f >> 4, c = (f & 15) * 8;
            uint4 v = make_uint4(0, 0, 0, 0);
            if (row0 + r < M) v = *(const uint4*)&A[(size_t)(row0 + r) * 128 + c];
            *(uint4*)&As[r * KP + c] = v;
        }
    } else {
        const float* A = (const float*)Av;
#pragma unroll
        for (int q = 0; q < 8; q++) {
            int f = tid + 256 * q;
            int r = f >> 5, c = (f & 31) * 4;
            float4 v = make_float4(0.f, 0.f, 0.f, 0.f);
            if (row0 + r < M) v = *(const float4*)&A[(size_t)(row0 + r) * 128 + c];
            ushort4 o;
            o.x = f2bf(v.x); o.y = f2bf(v.y); o.z = f2bf(v.z); o.w = f2bf(v.w);
            *(ushort4*)&As[r * KP + c] = o;
        }
    }
    for (int f = tid; f < NC * 16; f += 256) {
        int n = f >> 4, c = (f & 15) * 8;
        *(uint4*)&Bs[n * KP + c] = *(const uint4*)&Wt[n * 128 + c];
    }
    __syncthreads();

    const int wave = tid >> 6, lane = tid & 63;
    const int m = lane & 15, quad = lane >> 4;
    constexpr int CT = NC / 16;
    f32x4 acc[CT] = {};
    const short* arow = &As[(16 * wave + m) * KP + quad * 8];
    const short* brow = &Bs[m * KP + quad * 8];
#pragma unroll
    for (int k0 = 0; k0 < 128; k0 += 32) {
        bf16x8 a = *(const bf16x8*)&arow[k0];
#pragma unroll
        for (int c = 0; c < CT; c++) {
            bf16x8 b = *(const bf16x8*)&brow[(size_t)c * 16 * KP + k0];
            acc[c] = __builtin_amdgcn_mfma_f32_16x16x32_bf16(a, b, acc[c], 0, 0, 0);
        }
    }

    __syncthreads();
    short* Cs = As;
    const int rbase = 16 * wave + quad * 4;
    float dv[4];
#pragma unroll
    for (int r = 0; r < 4; r++) {
        int gr = row0 + rbase + r;
        dv[r] = dinv[gr < M ? gr : 0];
    }
#pragma unroll
    for (int c = 0; c < CT; c++)
#pragma unroll
        for (int r = 0; r < 4; r++)
            Cs[(rbase + r) * NC + 16 * c + m] = (short)f2bf(acc[c][r] * dv[r]);
    __syncthreads();
    for (int f = tid; f < 64 * NC / 8; f += 256) {
        int r = f / (NC / 8), c = (f % (NC / 8)) * 8;
        if (row0 + r < M)
            *(uint4*)&Out[(size_t)(row0 + r) * NC + c] = *(const uint4*)&Cs[r * NC + c];
    }
}

// Aggregate 128-wide bf16 rows (pre-scaled by dinv[src]).
// 2 nodes per wave: half-wave (32 lanes) per node, uint2 (8B) per lane covers
// cols 4sl..4sl+3. 8-deep unroll -> 16 row-gathers in flight per wave.
// Inner loop is PURE ADD (norm factorized into the GEMM epilogue).
__global__ __launch_bounds__(256) void k_agg128b(const int* __restrict__ csr_src,
                                                 const int* __restrict__ rowptr,
                                                 const int* __restrict__ cnt,
                                                 const float* __restrict__ dinv,
                                                 const unsigned* __restrict__ xw,
                                                 const float* __restrict__ bias,
                                                 unsigned* __restrict__ h1, int N) {
    const int lane = threadIdx.x & 63;
    const int wid = (blockIdx.x * blockDim.x + threadIdx.x) >> 6;
    const int h = lane >> 5, sl = lane & 31;
    const int i = wid * 2 + h;
    if (i >= N) return;
    const float di = dinv[i];
    uint2 u = *(const uint2*)&xw[(size_t)i * 64 + 2 * sl];   // self row (already *di)
    float a0 = bf_lo(u.x), a1 = bf_hi(u.x);
    float a2 = bf_lo(u.y), a3 = bf_hi(u.y);
    const int start = rowptr[i], cn = cnt[i];
    int j = 0;
    for (; j + 8 <= cn; j += 8) {
        int s[8]; uint2 uu[8];
#pragma unroll
        for (int k = 0; k < 8; k++) s[k] = csr_src[start + j + k];
#pragma unroll
        for (int k = 0; k < 8; k++) uu[k] = *(const uint2*)&xw[(size_t)s[k] * 64 + 2 * sl];
#pragma unroll
        for (int k = 0; k < 8; k++) {
            a0 += bf_lo(uu[k].x); a1 += bf_hi(uu[k].x);
            a2 += bf_lo(uu[k].y); a3 += bf_hi(uu[k].y);
        }
    }
    for (; j + 2 <= cn; j += 2) {
        int s0 = csr_src[start + j], s1 = csr_src[start + j + 1];
        uint2 u0 = *(const uint2*)&xw[(size_t)s0 * 64 + 2 * sl];
        uint2 u1 = *(const uint2*)&xw[(size_t)s1 * 64 + 2 * sl];
        a0 += bf_lo(u0.x) + bf_lo(u1.x); a1 += bf_hi(u0.x) + bf_hi(u1.x);
        a2 += bf_lo(u0.y) + bf_lo(u1.y); a3 += bf_hi(u0.y) + bf_hi(u1.y);
    }
    if (j < cn) {
        int s0 = csr_src[start + j];
        uint2 u0 = *(const uint2*)&xw[(size_t)s0 * 64 + 2 * sl];
        a0 += bf_lo(u0.x); a1 += bf_hi(u0.x);
        a2 += bf_lo(u0.y); a3 += bf_hi(u0.y);
    }
    float4 b = *(const float4*)&bias[4 * sl];
    float r0 = fmaxf(di * a0 + b.x, 0.f);    // ReLU folded (layer-1 epilogue)
    float r1 = fmaxf(di * a1 + b.y, 0.f);
    float r2 = fmaxf(di * a2 + b.z, 0.f);
    float r3 = fmaxf(di * a3 + b.w, 0.f);
    uint2 o;
    o.x = (unsigned)f2bf(r0) | ((unsigned)f2bf(r1) << 16);
    o.y = (unsigned)f2bf(r2) | ((unsigned)f2bf(r3) << 16);
    *(uint2*)&h1[(size_t)i * 64 + 2 * sl] = o;
}

// Aggregate 64-wide bf16 rows (pre-scaled). 2 nodes per wave; per node two
// 16-lane edge-substreams, uint2 per lane (cols 4sl..4sl+3), 4-deep unroll
// each -> 16 row-gathers in flight per wave. log_softmax fused.
__global__ __launch_bounds__(256) void k_agg64b(const int* __restrict__ csr_src,
                                                const int* __restrict__ rowptr,
                                                const int* __restrict__ cnt,
                                                const float* __restrict__ dinv,
                                                const unsigned* __restrict__ xw,
                                                const float* __restrict__ bias,
                                                float* __restrict__ out, int N) {
    const int lane = threadIdx.x & 63;
    const int wid = (blockIdx.x * blockDim.x + threadIdx.x) >> 6;
    const int h = lane >> 5;          // node select within wave
    const int q = (lane >> 4) & 1;    // edge substream
    const int sl = lane & 15;         // covers cols 4sl..4sl+3
    const int i = wid * 2 + h;
    if (i >= N) return;
    const float di = dinv[i];
    float a0 = 0.f, a1 = 0.f, a2 = 0.f, a3 = 0.f;
    if (q == 0) {
        uint2 u = *(const uint2*)&xw[(size_t)i * 32 + 2 * sl];   // self row
        a0 = bf_lo(u.x); a1 = bf_hi(u.x); a2 = bf_lo(u.y); a3 = bf_hi(u.y);
    }
    const int start = rowptr[i], cn = cnt[i];
    int e = q;
    for (; e + 6 < cn; e += 8) {      // each substream: edges e, e+2, e+4, e+6
        int s[4]; uint2 uu[4];
#pragma unroll
        for (int k = 0; k < 4; k++) s[k] = csr_src[start + e + 2 * k];
#pragma unroll
        for (int k = 0; k < 4; k++) uu[k] = *(const uint2*)&xw[(size_t)s[k] * 32 + 2 * sl];
#pragma unroll
        for (int k = 0; k < 4; k++) {
            a0 += bf_lo(uu[k].x); a1 += bf_hi(uu[k].x);
            a2 += bf_lo(uu[k].y); a3 += bf_hi(uu[k].y);
        }
    }
    for (; e < cn; e += 2) {
        int s0 = csr_src[start + e];
        uint2 u0 = *(const uint2*)&xw[(size_t)s0 * 32 + 2 * sl];
        a0 += bf_lo(u0.x); a1 += bf_hi(u0.x);
        a2 += bf_lo(u0.y); a3 += bf_hi(u0.y);
    }
    a0 += __shfl_xor(a0, 16); a1 += __shfl_xor(a1, 16);
    a2 += __shfl_xor(a2, 16); a3 += __shfl_xor(a3, 16);
    float4 b = *(const float4*)&bias[4 * sl];
    float v0 = di * a0 + b.x, v1 = di * a1 + b.y;
    float v2 = di * a2 + b.z, v3 = di * a3 + b.w;
    // fused log_softmax over 64 cols (4 per lane, duplicated across substreams)
    float m = fmaxf(fmaxf(v0, v1), fmaxf(v2, v3));
#pragma unroll
    for (int o = 8; o > 0; o >>= 1) m = fmaxf(m, __shfl_xor(m, o));
    float s2 = expf(v0 - m) + expf(v1 - m) + expf(v2 - m) + expf(v3 - m);
#pragma unroll
    for (int o = 8; o > 0; o >>= 1) s2 += __shfl_xor(s2, o);
    float ls = m + logf(s2);
    if (q == 0)
        *(float4*)&out[(size_t)i * 64 + 4 * sl] =
            make_float4(v0 - ls, v1 - ls, v2 - ls, v3 - ls);
}

extern "C" void kernel_launch(void* const* d_in, const int* in_sizes, int n_in,
                              void* d_out, int out_size, void* d_ws, size_t ws_size,
                              hipStream_t stream) {
    const float* x  = (const float*)d_in[0];
    const int*   ei = (const int*)d_in[1];
    const float* W1 = (const float*)d_in[2];
    const float* b1 = (const float*)d_in[3];
    const float* W2 = (const float*)d_in[4];
    const float* b2 = (const float*)d_in[5];

    const int N = in_sizes[0] / 128;   // 100000
    const int E = in_sizes[1] / 2;     // 1600000
    const int* src = ei;
    const int* dst = ei + E;
    const int B = (N + 255) >> BSHIFT; // 391 buckets

    char* ws = (char*)d_ws;
    size_t off = 0;
    auto alloc = [&](size_t bytes) {
        void* p = ws + off;
        off += (bytes + 255) & ~(size_t)255;
        return p;
    };
    int*            bcnt    = (int*)alloc(MAXB * 4 * 2);    // bcnt + bfill adjacent
    int*            bfill   = bcnt + MAXB;
    int*            boff    = (int*)alloc((MAXB + 1) * 4);
    int*            deg     = (int*)alloc((size_t)N * 4);
    float*          dinv    = (float*)alloc((size_t)N * 4);
    int*            rowptr  = (int*)alloc((size_t)N * 4);
    int*            csr_src = (int*)alloc((size_t)E * 4);
    unsigned*       pairs   = (unsigned*)alloc((size_t)E * 4);
    unsigned short* Wt1     = (unsigned short*)alloc(128 * 128 * 2);
    unsigned short* Wt2     = (unsigned short*)alloc(64 * 128 * 2);
    unsigned short* xw1     = (unsigned short*)alloc((size_t)N * 128 * 2);  // bf16; reused as hw2
    unsigned short* h1      = (unsigned short*)alloc((size_t)N * 128 * 2);  // bf16
    unsigned short* hw2     = xw1;
    float*          out     = (float*)d_out;

    hipMemsetAsync(bcnt, 0, MAXB * 4 * 2, stream);

    // CSR build (bucketed, XCD-local)
    k_bcount<<<512, THREADS, 0, stream>>>(dst, E, B, bcnt);
    k_bscan<<<1, MAXB, 0, stream>>>(bcnt, B, boff);
    k_bscatter<<<(E + 8191) / 8192, THREADS, 0, stream>>>(src, dst, E, B, boff, bfill, pairs);
    k_bbuild<<<B, THREADS, 0, stream>>>(pairs, boff, N, deg, dinv, rowptr, csr_src);

    k_castW<<<96, THREADS, 0, stream>>>(W1, W2, Wt1, Wt2);

    // grids for 2-nodes-per-wave aggregation: ceil(N/2) waves, 4 waves/block
    const int aggBlocks = (N + 7) / 8;

    // Layer 1
    k_gemm_mfma<128, false><<<(N + 63) / 64, THREADS, 0, stream>>>(x, Wt1, dinv, xw1, N);
    k_agg128b<<<aggBlocks, THREADS, 0, stream>>>(
        csr_src, rowptr, deg, dinv, (const unsigned*)xw1, b1, (unsigned*)h1, N);

    // Layer 2 (+ fused log_softmax)
    k_gemm_mfma<64, true><<<(N + 63) / 64, THREADS, 0, stream>>>(h1, Wt2, dinv, hw2, N);
    k_agg64b<<<aggBlocks, THREADS, 0, stream>>>(
        csr_src, rowptr, deg, dinv, (const unsigned*)hw2, b2, out, N);
}

// Round 2
// 287.313 us; speedup vs baseline: 1.1347x; 1.0190x over previous
//
#include <hip/hip_runtime.h>
#include <cmath>

// GCN 2-layer forward on MI355X — round 7: padded CSR (edge lists padded to x8 with
// a dummy zero-row source) -> branch-free aggregation with software-pipelined index
// prefetch (one memory latency per 8 edges instead of two, no tail serialization).
// Pipeline: bcount -> bscan -> bscatter(packed) -> bbuild(padded CSR) ->
//           gemm1_mfma(x@W1 * dinv -> bf16, zero-row epi) -> agg128 (uniform loop) ->
//           gemm2_mfma(h1@W2 * dinv -> bf16, zero-row epi) -> agg64+log_softmax fused.

#define THREADS 256
#define BSHIFT 8                      // 256 nodes per bucket
#define MAXB 512                      // >= ceil(N / 256)
#define PADSLACK 1792                 // 256 nodes * 7 max pad per bucket

__device__ __forceinline__ unsigned short f2bf(float f) {
    union { float f; unsigned u; } v; v.f = f;
    unsigned r = v.u + 0x7FFFu + ((v.u >> 16) & 1u);   // round-nearest-even
    return (unsigned short)(r >> 16);
}
__device__ __forceinline__ float bf_lo(unsigned u) {
    union { unsigned u; float f; } v; v.u = u << 16; return v.f;
}
__device__ __forceinline__ float bf_hi(unsigned u) {
    union { unsigned u; float f; } v; v.u = u & 0xFFFF0000u; return v.f;
}

// ---- bucket count: LDS histogram, flush once per block ----
__global__ __launch_bounds__(256) void k_bcount(const int* __restrict__ dst, int E, int B,
                                                int* __restrict__ bcnt) {
    __shared__ int lc[MAXB];
    for (int i = threadIdx.x; i < MAXB; i += 256) lc[i] = 0;
    __syncthreads();
    for (int e = blockIdx.x * blockDim.x + threadIdx.x; e < E; e += gridDim.x * blockDim.x)
        atomicAdd(&lc[dst[e] >> BSHIFT], 1);
    __syncthreads();
    for (int b = threadIdx.x; b < B; b += 256)
        if (lc[b]) atomicAdd(&bcnt[b], lc[b]);
}

// ---- exclusive scan of bcnt[B] -> boff[B+1], single block of 512 ----
__global__ void k_bscan(const int* __restrict__ bcnt, int B, int* __restrict__ boff) {
    __shared__ int sh[MAXB];
    const int t = threadIdx.x;
    int v = (t < B) ? bcnt[t] : 0;
    sh[t] = v; __syncthreads();
    for (int o = 1; o < MAXB; o <<= 1) {
        int add = (t >= o) ? sh[t - o] : 0;
        __syncthreads();
        sh[t] += add;
        __syncthreads();
    }
    if (t < B) boff[t] = sh[t] - v;
    if (t == B - 1) boff[B] = sh[t];
}

// ---- scatter edges into bucket-contiguous packed records (loc<<24 | src) ----
__global__ __launch_bounds__(256) void k_bscatter(const int* __restrict__ src,
                                                  const int* __restrict__ dst, int E, int B,
                                                  const int* __restrict__ boff,
                                                  int* __restrict__ bfill,
                                                  unsigned* __restrict__ pairs) {
    __shared__ int lc[MAXB];     // per-block bucket count, then per-bucket rank
    __shared__ int lbase[MAXB];  // global reservation base within bucket
    const int tid = threadIdx.x;
    const int e0 = blockIdx.x * 8192;
    for (int i = tid; i < MAXB; i += 256) lc[i] = 0;
    __syncthreads();
#pragma unroll
    for (int k = 0; k < 32; k++) {
        int e = e0 + k * 256 + tid;
        if (e < E) atomicAdd(&lc[dst[e] >> BSHIFT], 1);
    }
    __syncthreads();
    for (int b = tid; b < B; b += 256)
        lbase[b] = lc[b] ? atomicAdd(&bfill[b], lc[b]) : 0;
    __syncthreads();
    for (int i = tid; i < MAXB; i += 256) lc[i] = 0;  // reuse as rank
    __syncthreads();
#pragma unroll
    for (int k = 0; k < 32; k++) {
        int e = e0 + k * 256 + tid;
        if (e < E) {
            int s = src[e], d = dst[e];
            int b = d >> BSHIFT;
            int r = atomicAdd(&lc[b], 1);
            pairs[(size_t)boff[b] + lbase[b] + r] =
                ((unsigned)(d & 255) << 24) | (unsigned)s;   // src < 2^24
        }
    }
}

// ---- per-bucket padded-CSR build: one block per bucket ----
// Each node's slot count is padded to a multiple of 8; pad slots hold dummy src N
// (zero feature row), so the aggregation loop is branch-free with no tail.
__global__ __launch_bounds__(256) void k_bbuild(const unsigned* __restrict__ pairs,
                                                const int* __restrict__ boff, int N,
                                                int* __restrict__ deg,
                                                float* __restrict__ dinv,
                                                int* __restrict__ rowptr,
                                                int* __restrict__ csr_src) {
    __shared__ int ldeg[256], lex[256], lrank[256];
    const int b = blockIdx.x, tid = threadIdx.x;
    const int node0 = b << BSHIFT;
    const int base = boff[b];
    const int pbase = base + b * PADSLACK;       // padded output base for this bucket
    const int cnt_e = boff[b + 1] - base;
    ldeg[tid] = 0;
    __syncthreads();
    for (int e = tid; e < cnt_e; e += 256)
        atomicAdd(&ldeg[pairs[base + e] >> 24], 1);
    __syncthreads();
    int v = ldeg[tid];
    int pd = (v + 7) & ~7;                       // padded degree
    lex[tid] = pd; __syncthreads();
    for (int o = 1; o < 256; o <<= 1) {
        int add = (tid >= o) ? lex[tid - o] : 0;
        __syncthreads();
        lex[tid] += add;
        __syncthreads();
    }
    int pexcl = lex[tid] - pd;                   // exclusive scan of padded degrees
    if (node0 + tid < N) {
        deg[node0 + tid] = v;
        dinv[node0 + tid] = rsqrtf((float)(v + 1));
        rowptr[node0 + tid] = pbase + pexcl;
    }
    __syncthreads();
    lex[tid] = pexcl;      // keep padded exclusive offsets for the scatter
    lrank[tid] = 0;
    __syncthreads();
    for (int e = tid; e < cnt_e; e += 256) {
        unsigned p = pairs[base + e];
        int loc = p >> 24;
        int r = atomicAdd(&lrank[loc], 1);
        csr_src[pbase + lex[loc] + r] = (int)(p & 0xFFFFFFu);
    }
    // fill pad slots with the dummy source (row N is all-zeros)
    for (int p = v; p < pd; p++)
        csr_src[pbase + pexcl + p] = N;
}

// Wt1[n][k] = bf16(W1[k][n]) (128x128), Wt2[n][k] = bf16(W2[k][n]) (64x128)
__global__ void k_castW(const float* __restrict__ W1, const float* __restrict__ W2,
                        unsigned short* __restrict__ Wt1, unsigned short* __restrict__ Wt2) {
    int idx = blockIdx.x * blockDim.x + threadIdx.x;
    if (idx < 16384) {
        int n = idx >> 7, k = idx & 127;
        Wt1[idx] = f2bf(W1[k * 128 + n]);
    } else if (idx < 16384 + 8192) {
        int t = idx - 16384;
        int n = t >> 7, k = t & 127;
        Wt2[t] = f2bf(W2[k * 64 + n]);
    }
}

// C[M x NC](bf16) = dinv[row] * (A[M x 128] @ Wt^T), Wt is [NC x 128] bf16.
// zrow (if non-null): NC bf16 entries zeroed by block 0 — the dummy feature row
// consumed by the downstream aggregation kernel.
typedef __attribute__((ext_vector_type(8))) short bf16x8;
typedef __attribute__((ext_vector_type(4))) float f32x4;

template <int NC, bool A_BF16>
__global__ __launch_bounds__(256) void k_gemm_mfma(const void* __restrict__ Av,
                                                   const unsigned short* __restrict__ Wt,
                                                   const float* __restrict__ dinv,
                                                   unsigned short* __restrict__ Out,
                                                   unsigned short* __restrict__ zrow,
                                                   int M) {
    constexpr int KP = 136;                 // padded k-stride
    __shared__ __align__(16) short As[64 * KP];
    __shared__ __align__(16) short Bs[NC * KP];
    const int tid = threadIdx.x;
    const int row0 = blockIdx.x * 64;

    if (blockIdx.x == 0 && tid < NC) zrow[tid] = 0;   // dummy zero row

    if (A_BF16) {
        const unsigned short* A = (const unsigned short*)Av;
#pragma unroll
        for (int q = 0; q < 4; q++) {
            int f = tid + 256 * q;
            int r = f >> 4, c = (f & 15) * 8;
            uint4 v = make_uint4(0, 0, 0, 0);
            if (row0 + r < M) v = *(const uint4*)&A[(size_t)(row0 + r) * 128 + c];
            *(uint4*)&As[r * KP + c] = v;
        }
    } else {
        const float* A = (const float*)Av;
#pragma unroll
        for (int q = 0; q < 8; q++) {
            int f = tid + 256 * q;
            int r = f >> 5, c = (f & 31) * 4;
            float4 v = make_float4(0.f, 0.f, 0.f, 0.f);
            if (row0 + r < M) v = *(const float4*)&A[(size_t)(row0 + r) * 128 + c];
            ushort4 o;
            o.x = f2bf(v.x); o.y = f2bf(v.y); o.z = f2bf(v.z); o.w = f2bf(v.w);
            *(ushort4*)&As[r * KP + c] = o;
        }
    }
    for (int f = tid; f < NC * 16; f += 256) {
        int n = f >> 4, c = (f & 15) * 8;
        *(uint4*)&Bs[n * KP + c] = *(const uint4*)&Wt[n * 128 + c];
    }
    __syncthreads();

    const int wave = tid >> 6, lane = tid & 63;
    const int m = lane & 15, quad = lane >> 4;
    constexpr int CT = NC / 16;
    f32x4 acc[CT] = {};
    const short* arow = &As[(16 * wave + m) * KP + quad * 8];
    const short* brow = &Bs[m * KP + quad * 8];
#pragma unroll
    for (int k0 = 0; k0 < 128; k0 += 32) {
        bf16x8 a = *(const bf16x8*)&arow[k0];
#pragma unroll
        for (int c = 0; c < CT; c++) {
            bf16x8 b = *(const bf16x8*)&brow[(size_t)c * 16 * KP + k0];
            acc[c] = __builtin_amdgcn_mfma_f32_16x16x32_bf16(a, b, acc[c], 0, 0, 0);
        }
    }

    __syncthreads();
    short* Cs = As;
    const int rbase = 16 * wave + quad * 4;
    float dv[4];
#pragma unroll
    for (int r = 0; r < 4; r++) {
        int gr = row0 + rbase + r;
        dv[r] = dinv[gr < M ? gr : 0];
    }
#pragma unroll
    for (int c = 0; c < CT; c++)
#pragma unroll
        for (int r = 0; r < 4; r++)
            Cs[(rbase + r) * NC + 16 * c + m] = (short)f2bf(acc[c][r] * dv[r]);
    __syncthreads();
    for (int f = tid; f < 64 * NC / 8; f += 256) {
        int r = f / (NC / 8), c = (f % (NC / 8)) * 8;
        if (row0 + r < M)
            *(uint4*)&Out[(size_t)(row0 + r) * NC + c] = *(const uint4*)&Cs[r * NC + c];
    }
}

// Aggregate 128-wide bf16 rows (pre-scaled by dinv[src]).
// 2 nodes/wave, half-wave per node, uint2 per lane. Edge lists are padded to x8
// with dummy src N (zero row) -> branch-free uniform loop; index loads for the
// next iteration are software-pipelined against the current gathers.
__global__ __launch_bounds__(256) void k_agg128b(const int* __restrict__ csr_src,
                                                 const int* __restrict__ rowptr,
                                                 const int* __restrict__ cnt,
                                                 const float* __restrict__ dinv,
                                                 const unsigned* __restrict__ xw,
                                                 const float* __restrict__ bias,
                                                 unsigned* __restrict__ h1, int N) {
    const int lane = threadIdx.x & 63;
    const int wid = (blockIdx.x * blockDim.x + threadIdx.x) >> 6;
    const int h = lane >> 5, sl = lane & 31;
    const int i = wid * 2 + h;
    if (i >= N) return;
    const float di = dinv[i];
    uint2 u = *(const uint2*)&xw[(size_t)i * 64 + 2 * sl];   // self row (already *di)
    float a0 = bf_lo(u.x), a1 = bf_hi(u.x);
    float a2 = bf_lo(u.y), a3 = bf_hi(u.y);
    const int start = rowptr[i];
    const int pc = (cnt[i] + 7) & ~7;          // padded count; slots are dummy-filled
    int s[8];
#pragma unroll
    for (int k = 0; k < 8; k++) s[k] = csr_src[start + k];
    for (int j = 0; j < pc; j += 8) {
        uint2 uu[8];
#pragma unroll
        for (int k = 0; k < 8; k++) uu[k] = *(const uint2*)&xw[(size_t)s[k] * 64 + 2 * sl];
#pragma unroll
        for (int k = 0; k < 8; k++) s[k] = csr_src[start + j + 8 + k];  // prefetch (load-only overread)
#pragma unroll
        for (int k = 0; k < 8; k++) {
            a0 += bf_lo(uu[k].x); a1 += bf_hi(uu[k].x);
            a2 += bf_lo(uu[k].y); a3 += bf_hi(uu[k].y);
        }
    }
    float4 b = *(const float4*)&bias[4 * sl];
    float r0 = fmaxf(di * a0 + b.x, 0.f);    // ReLU folded (layer-1 epilogue)
    float r1 = fmaxf(di * a1 + b.y, 0.f);
    float r2 = fmaxf(di * a2 + b.z, 0.f);
    float r3 = fmaxf(di * a3 + b.w, 0.f);
    uint2 o;
    o.x = (unsigned)f2bf(r0) | ((unsigned)f2bf(r1) << 16);
    o.y = (unsigned)f2bf(r2) | ((unsigned)f2bf(r3) << 16);
    *(uint2*)&h1[(size_t)i * 64 + 2 * sl] = o;
}

// Aggregate 64-wide bf16 rows (pre-scaled). 2 nodes/wave; per node two 16-lane
// edge-substreams, uint2 per lane, 4-deep each, padded + pipelined like agg128.
// log_softmax fused into the epilogue.
__global__ __launch_bounds__(256) void k_agg64b(const int* __restrict__ csr_src,
                                                const int* __restrict__ rowptr,
                                                const int* __restrict__ cnt,
                                                const float* __restrict__ dinv,
                                                const unsigned* __restrict__ xw,
                                                const float* __restrict__ bias,
                                                float* __restrict__ out, int N) {
    const int lane = threadIdx.x & 63;
    const int wid = (blockIdx.x * blockDim.x + threadIdx.x) >> 6;
    const int h = lane >> 5;          // node select within wave
    const int q = (lane >> 4) & 1;    // edge substream
    const int sl = lane & 15;         // covers cols 4sl..4sl+3
    const int i = wid * 2 + h;
    if (i >= N) return;
    const float di = dinv[i];
    float a0 = 0.f, a1 = 0.f, a2 = 0.f, a3 = 0.f;
    if (q == 0) {
        uint2 u = *(const uint2*)&xw[(size_t)i * 32 + 2 * sl];   // self row
        a0 = bf_lo(u.x); a1 = bf_hi(u.x); a2 = bf_lo(u.y); a3 = bf_hi(u.y);
    }
    const int start = rowptr[i];
    const int pc = (cnt[i] + 7) & ~7;
    int s[4];
#pragma unroll
    for (int k = 0; k < 4; k++) s[k] = csr_src[start + q + 2 * k];
    for (int e = 0; e < pc; e += 8) {      // each substream: 4 edges per iter
        uint2 uu[4];
#pragma unroll
        for (int k = 0; k < 4; k++) uu[k] = *(const uint2*)&xw[(size_t)s[k] * 32 + 2 * sl];
#pragma unroll
        for (int k = 0; k < 4; k++) s[k] = csr_src[start + e + 8 + q + 2 * k];
#pragma unroll
        for (int k = 0; k < 4; k++) {
            a0 += bf_lo(uu[k].x); a1 += bf_hi(uu[k].x);
            a2 += bf_lo(uu[k].y); a3 += bf_hi(uu[k].y);
        }
    }
    a0 += __shfl_xor(a0, 16); a1 += __shfl_xor(a1, 16);
    a2 += __shfl_xor(a2, 16); a3 += __shfl_xor(a3, 16);
    float4 b = *(const float4*)&bias[4 * sl];
    float v0 = di * a0 + b.x, v1 = di * a1 + b.y;
    float v2 = di * a2 + b.z, v3 = di * a3 + b.w;
    // fused log_softmax over 64 cols (4 per lane, duplicated across substreams)
    float m = fmaxf(fmaxf(v0, v1), fmaxf(v2, v3));
#pragma unroll
    for (int o = 8; o > 0; o >>= 1) m = fmaxf(m, __shfl_xor(m, o));
    float s2 = expf(v0 - m) + expf(v1 - m) + expf(v2 - m) + expf(v3 - m);
#pragma unroll
    for (int o = 8; o > 0; o >>= 1) s2 += __shfl_xor(s2, o);
    float ls = m + logf(s2);
    if (q == 0)
        *(float4*)&out[(size_t)i * 64 + 4 * sl] =
            make_float4(v0 - ls, v1 - ls, v2 - ls, v3 - ls);
}

extern "C" void kernel_launch(void* const* d_in, const int* in_sizes, int n_in,
                              void* d_out, int out_size, void* d_ws, size_t ws_size,
                              hipStream_t stream) {
    const float* x  = (const float*)d_in[0];
    const int*   ei = (const int*)d_in[1];
    const float* W1 = (const float*)d_in[2];
    const float* b1 = (const float*)d_in[3];
    const float* W2 = (const float*)d_in[4];
    const float* b2 = (const float*)d_in[5];

    const int N = in_sizes[0] / 128;   // 100000
    const int E = in_sizes[1] / 2;     // 1600000
    const int* src = ei;
    const int* dst = ei + E;
    const int B = (N + 255) >> BSHIFT; // 391 buckets

    char* ws = (char*)d_ws;
    size_t off = 0;
    auto alloc = [&](size_t bytes) {
        void* p = ws + off;
        off += (bytes + 255) & ~(size_t)255;
        return p;
    };
    int*            bcnt    = (int*)alloc(MAXB * 4 * 2);    // bcnt + bfill adjacent
    int*            bfill   = bcnt + MAXB;
    int*            boff    = (int*)alloc((MAXB + 1) * 4);
    int*            deg     = (int*)alloc((size_t)N * 4);
    float*          dinv    = (float*)alloc((size_t)N * 4);
    int*            rowptr  = (int*)alloc((size_t)N * 4);
    // padded CSR: per-bucket slack PADSLACK + 64 ints of end slack for prefetch overread
    int*            csr_src = (int*)alloc(((size_t)E + (size_t)B * PADSLACK + 64) * 4);
    unsigned*       pairs   = (unsigned*)alloc((size_t)E * 4);
    unsigned short* Wt1     = (unsigned short*)alloc(128 * 128 * 2);
    unsigned short* Wt2     = (unsigned short*)alloc(64 * 128 * 2);
    unsigned short* xw1     = (unsigned short*)alloc((size_t)(N + 1) * 128 * 2);  // +1: dummy zero row
    unsigned short* h1      = (unsigned short*)alloc((size_t)N * 128 * 2);        // bf16
    unsigned short* hw2     = xw1;     // reused; dummy row N (64-col layout) zeroed by gemm2
    float*          out     = (float*)d_out;

    hipMemsetAsync(bcnt, 0, MAXB * 4 * 2, stream);

    // CSR build (bucketed, XCD-local, padded to x8 per node)
    k_bcount<<<512, THREADS, 0, stream>>>(dst, E, B, bcnt);
    k_bscan<<<1, MAXB, 0, stream>>>(bcnt, B, boff);
    k_bscatter<<<(E + 8191) / 8192, THREADS, 0, stream>>>(src, dst, E, B, boff, bfill, pairs);
    k_bbuild<<<B, THREADS, 0, stream>>>(pairs, boff, N, deg, dinv, rowptr, csr_src);

    k_castW<<<96, THREADS, 0, stream>>>(W1, W2, Wt1, Wt2);

    // grids for 2-nodes-per-wave aggregation: ceil(N/2) waves, 4 waves/block
    const int aggBlocks = (N + 7) / 8;

    // Layer 1
    k_gemm_mfma<128, false><<<(N + 63) / 64, THREADS, 0, stream>>>(
        x, Wt1, dinv, xw1, xw1 + (size_t)N * 128, N);
    k_agg128b<<<aggBlocks, THREADS, 0, stream>>>(
        csr_src, rowptr, deg, dinv, (const unsigned*)xw1, b1, (unsigned*)h1, N);

    // Layer 2 (+ fused log_softmax); gemm2 zeroes hw2 dummy row (after agg128 consumed xw1)
    k_gemm_mfma<64, true><<<(N + 63) / 64, THREADS, 0, stream>>>(
        h1, Wt2, dinv, hw2, hw2 + (size_t)N * 64, N);
    k_agg64b<<<aggBlocks, THREADS, 0, stream>>>(
        csr_src, rowptr, deg, dinv, (const unsigned*)hw2, b2, out, N);
}

// Round 3
// 274.984 us; speedup vs baseline: 1.1855x; 1.0448x over previous
//
#include <hip/hip_runtime.h>
#include <cmath>

// GCN 2-layer forward on MI355X — round 8: instruction-rate attack on the gathers.
// uint4 (16B/lane) row gathers: agg128 = 4 nodes/wave (16 lanes/row), agg64 =
// 8 nodes/wave (8 lanes/row, no duplicate substreams). CSR stores BYTE offsets
// (src*256) so gather addressing is 1 VALU op. GEMM drops A-tile LDS staging
// (direct global->reg A fragments, f32->bf16 convert in reg, B-only LDS).

#define THREADS 256
#define BSHIFT 8                      // 256 nodes per bucket
#define MAXB 512                      // >= ceil(N / 256)
#define PADSLACK 1792                 // 256 nodes * 7 max pad per bucket

__device__ __forceinline__ unsigned short f2bf(float f) {
    union { float f; unsigned u; } v; v.f = f;
    unsigned r = v.u + 0x7FFFu + ((v.u >> 16) & 1u);   // round-nearest-even
    return (unsigned short)(r >> 16);
}
__device__ __forceinline__ float bf_lo(unsigned u) {
    union { unsigned u; float f; } v; v.u = u << 16; return v.f;
}
__device__ __forceinline__ float bf_hi(unsigned u) {
    union { unsigned u; float f; } v; v.u = u & 0xFFFF0000u; return v.f;
}

// ---- bucket count: LDS histogram, flush once per block ----
__global__ __launch_bounds__(256) void k_bcount(const int* __restrict__ dst, int E, int B,
                                                int* __restrict__ bcnt) {
    __shared__ int lc[MAXB];
    for (int i = threadIdx.x; i < MAXB; i += 256) lc[i] = 0;
    __syncthreads();
    for (int e = blockIdx.x * blockDim.x + threadIdx.x; e < E; e += gridDim.x * blockDim.x)
        atomicAdd(&lc[dst[e] >> BSHIFT], 1);
    __syncthreads();
    for (int b = threadIdx.x; b < B; b += 256)
        if (lc[b]) atomicAdd(&bcnt[b], lc[b]);
}

// ---- exclusive scan of bcnt[B] -> boff[B+1], single block of 512 ----
__global__ void k_bscan(const int* __restrict__ bcnt, int B, int* __restrict__ boff) {
    __shared__ int sh[MAXB];
    const int t = threadIdx.x;
    int v = (t < B) ? bcnt[t] : 0;
    sh[t] = v; __syncthreads();
    for (int o = 1; o < MAXB; o <<= 1) {
        int add = (t >= o) ? sh[t - o] : 0;
        __syncthreads();
        sh[t] += add;
        __syncthreads();
    }
    if (t < B) boff[t] = sh[t] - v;
    if (t == B - 1) boff[B] = sh[t];
}

// ---- scatter edges into bucket-contiguous packed records (loc<<24 | src) ----
__global__ __launch_bounds__(256) void k_bscatter(const int* __restrict__ src,
                                                  const int* __restrict__ dst, int E, int B,
                                                  const int* __restrict__ boff,
                                                  int* __restrict__ bfill,
                                                  unsigned* __restrict__ pairs) {
    __shared__ int lc[MAXB];     // per-block bucket count, then per-bucket rank
    __shared__ int lbase[MAXB];  // global reservation base within bucket
    const int tid = threadIdx.x;
    const int e0 = blockIdx.x * 8192;
    for (int i = tid; i < MAXB; i += 256) lc[i] = 0;
    __syncthreads();
#pragma unroll
    for (int k = 0; k < 32; k++) {
        int e = e0 + k * 256 + tid;
        if (e < E) atomicAdd(&lc[dst[e] >> BSHIFT], 1);
    }
    __syncthreads();
    for (int b = tid; b < B; b += 256)
        lbase[b] = lc[b] ? atomicAdd(&bfill[b], lc[b]) : 0;
    __syncthreads();
    for (int i = tid; i < MAXB; i += 256) lc[i] = 0;  // reuse as rank
    __syncthreads();
#pragma unroll
    for (int k = 0; k < 32; k++) {
        int e = e0 + k * 256 + tid;
        if (e < E) {
            int s = src[e], d = dst[e];
            int b = d >> BSHIFT;
            int r = atomicAdd(&lc[b], 1);
            pairs[(size_t)boff[b] + lbase[b] + r] =
                ((unsigned)(d & 255) << 24) | (unsigned)s;   // src < 2^24
        }
    }
}

// ---- per-bucket padded-CSR build: one block per bucket ----
// Node slot counts padded to x8; pad slots hold dummy src N (zero feature row).
// csr_off stores BYTE offsets (src*256) for 1-VALU gather addressing downstream.
__global__ __launch_bounds__(256) void k_bbuild(const unsigned* __restrict__ pairs,
                                                const int* __restrict__ boff, int N,
                                                int* __restrict__ deg,
                                                float* __restrict__ dinv,
                                                int* __restrict__ rowptr,
                                                unsigned* __restrict__ csr_off) {
    __shared__ int ldeg[256], lex[256], lrank[256];
    const int b = blockIdx.x, tid = threadIdx.x;
    const int node0 = b << BSHIFT;
    const int base = boff[b];
    const int pbase = base + b * PADSLACK;       // padded output base for this bucket
    const int cnt_e = boff[b + 1] - base;
    ldeg[tid] = 0;
    __syncthreads();
    for (int e = tid; e < cnt_e; e += 256)
        atomicAdd(&ldeg[pairs[base + e] >> 24], 1);
    __syncthreads();
    int v = ldeg[tid];
    int pd = (v + 7) & ~7;                       // padded degree
    lex[tid] = pd; __syncthreads();
    for (int o = 1; o < 256; o <<= 1) {
        int add = (tid >= o) ? lex[tid - o] : 0;
        __syncthreads();
        lex[tid] += add;
        __syncthreads();
    }
    int pexcl = lex[tid] - pd;                   // exclusive scan of padded degrees
    if (node0 + tid < N) {
        deg[node0 + tid] = v;
        dinv[node0 + tid] = rsqrtf((float)(v + 1));
        rowptr[node0 + tid] = pbase + pexcl;
    }
    __syncthreads();
    lex[tid] = pexcl;      // keep padded exclusive offsets for the scatter
    lrank[tid] = 0;
    __syncthreads();
    for (int e = tid; e < cnt_e; e += 256) {
        unsigned p = pairs[base + e];
        int loc = p >> 24;
        int r = atomicAdd(&lrank[loc], 1);
        csr_off[pbase + lex[loc] + r] = (p & 0xFFFFFFu) << 8;   // byte offset (256B rows)
    }
    // fill pad slots with the dummy source (row N is all-zeros)
    for (int p = v; p < pd; p++)
        csr_off[pbase + pexcl + p] = ((unsigned)N) << 8;
}

// Wt1[n][k] = bf16(W1[k][n]) (128x128), Wt2[n][k] = bf16(W2[k][n]) (64x128)
__global__ void k_castW(const float* __restrict__ W1, const float* __restrict__ W2,
                        unsigned short* __restrict__ Wt1, unsigned short* __restrict__ Wt2) {
    int idx = blockIdx.x * blockDim.x + threadIdx.x;
    if (idx < 16384) {
        int n = idx >> 7, k = idx & 127;
        Wt1[idx] = f2bf(W1[k * 128 + n]);
    } else if (idx < 16384 + 8192) {
        int t = idx - 16384;
        int n = t >> 7, k = t & 127;
        Wt2[t] = f2bf(W2[k * 64 + n]);
    }
}

// C[M x NC](bf16) = dinv[row] * (A[M x 128] @ Wt^T), Wt is [NC x 128] bf16.
// A fragments loaded DIRECTLY global->reg (no LDS staging, f32->bf16 in reg);
// only B tile + epilogue transpose use LDS. zrow: dummy zero row for aggregation.
typedef __attribute__((ext_vector_type(8))) short bf16x8;
typedef __attribute__((ext_vector_type(4))) float f32x4;

template <int NC, bool A_BF16>
__global__ __launch_bounds__(256) void k_gemm_mfma(const void* __restrict__ Av,
                                                   const unsigned short* __restrict__ Wt,
                                                   const float* __restrict__ dinv,
                                                   unsigned short* __restrict__ Out,
                                                   unsigned short* __restrict__ zrow,
                                                   int M) {
    constexpr int KP = 136;                 // padded k-stride (17x16B: conflict-even)
    __shared__ __align__(16) short Bs[NC * KP];
    const int tid = threadIdx.x;
    const int row0 = blockIdx.x * 64;

    if (blockIdx.x == 0 && tid < NC) zrow[tid] = 0;   // dummy zero row

    // stage B tile (NC x 128 bf16)
    for (int f = tid; f < NC * 16; f += 256) {
        int n = f >> 4, c = (f & 15) * 8;
        *(uint4*)&Bs[n * KP + c] = *(const uint4*)&Wt[n * 128 + c];
    }

    const int wave = tid >> 6, lane = tid & 63;
    const int m = lane & 15, quad = lane >> 4;
    const int row = row0 + 16 * wave + m;
    const int rowc = row < M ? row : (M - 1);          // clamp: garbage rows masked at store

    // A fragments: 4 k-steps x bf16x8, straight from global
    bf16x8 afr[4];
    if (A_BF16) {
        const unsigned short* A = (const unsigned short*)Av;
#pragma unroll
        for (int k = 0; k < 4; k++)
            afr[k] = *(const bf16x8*)&A[(size_t)rowc * 128 + quad * 8 + 32 * k];
    } else {
        const float* A = (const float*)Av;
#pragma unroll
        for (int k = 0; k < 4; k++) {
            float4 lo = *(const float4*)&A[(size_t)rowc * 128 + quad * 8 + 32 * k];
            float4 hi = *(const float4*)&A[(size_t)rowc * 128 + quad * 8 + 32 * k + 4];
            bf16x8 a;
            a[0] = (short)f2bf(lo.x); a[1] = (short)f2bf(lo.y);
            a[2] = (short)f2bf(lo.z); a[3] = (short)f2bf(lo.w);
            a[4] = (short)f2bf(hi.x); a[5] = (short)f2bf(hi.y);
            a[6] = (short)f2bf(hi.z); a[7] = (short)f2bf(hi.w);
            afr[k] = a;
        }
    }
    __syncthreads();    // Bs ready

    constexpr int CT = NC / 16;
    f32x4 acc[CT] = {};
    const short* brow = &Bs[m * KP + quad * 8];
#pragma unroll
    for (int k = 0; k < 4; k++) {
#pragma unroll
        for (int c = 0; c < CT; c++) {
            bf16x8 b = *(const bf16x8*)&brow[(size_t)c * 16 * KP + 32 * k];
            acc[c] = __builtin_amdgcn_mfma_f32_16x16x32_bf16(afr[k], b, acc[c], 0, 0, 0);
        }
    }

    __syncthreads();    // all waves done reading Bs -> reuse as Cs
    short* Cs = Bs;     // 64 x NC shorts fits in NC x KP
    const int rbase = 16 * wave + quad * 4;
    float dv[4];
#pragma unroll
    for (int r = 0; r < 4; r++) {
        int gr = row0 + rbase + r;
        dv[r] = dinv[gr < M ? gr : 0];
    }
#pragma unroll
    for (int c = 0; c < CT; c++)
#pragma unroll
        for (int r = 0; r < 4; r++)
            Cs[(rbase + r) * NC + 16 * c + m] = (short)f2bf(acc[c][r] * dv[r]);
    __syncthreads();
    for (int f = tid; f < 64 * NC / 8; f += 256) {
        int r = f / (NC / 8), c = (f % (NC / 8)) * 8;
        if (row0 + r < M)
            *(uint4*)&Out[(size_t)(row0 + r) * NC + c] = *(const uint4*)&Cs[r * NC + c];
    }
}

// Aggregate 128-wide bf16 rows (pre-scaled by dinv[src]).
// 4 nodes/wave: 16 lanes per node, uint4 (16B) per lane covers cols 8sl..8sl+7.
// csr_off holds byte offsets; padded x8 lists -> branch-free pipelined loop.
__global__ __launch_bounds__(256) void k_agg128b(const unsigned* __restrict__ csr_off,
                                                 const int* __restrict__ rowptr,
                                                 const int* __restrict__ cnt,
                                                 const float* __restrict__ dinv,
                                                 const unsigned char* __restrict__ xwb,
                                                 const float* __restrict__ bias,
                                                 unsigned* __restrict__ h1, int N) {
    const int lane = threadIdx.x & 63;
    const int wid = (blockIdx.x * blockDim.x + threadIdx.x) >> 6;
    const int g = lane >> 4, sl = lane & 15;
    const int i = wid * 4 + g;
    if (i >= N) return;
    const float di = dinv[i];
    const int slb = sl * 16;
    uint4 u = *(const uint4*)(xwb + ((size_t)i << 8) + slb);   // self row (already *di)
    float a0 = bf_lo(u.x), a1 = bf_hi(u.x), a2 = bf_lo(u.y), a3 = bf_hi(u.y);
    float a4 = bf_lo(u.z), a5 = bf_hi(u.z), a6 = bf_lo(u.w), a7 = bf_hi(u.w);
    const int start = rowptr[i];
    const int pc = (cnt[i] + 7) & ~7;          // padded count; pad slots dummy-filled
    unsigned s[8];
#pragma unroll
    for (int k = 0; k < 8; k++) s[k] = csr_off[start + k];
    for (int j = 0; j < pc; j += 8) {
        uint4 uu[8];
#pragma unroll
        for (int k = 0; k < 8; k++) uu[k] = *(const uint4*)(xwb + s[k] + slb);
#pragma unroll
        for (int k = 0; k < 8; k++) s[k] = csr_off[start + j + 8 + k];  // prefetch (overread ok)
#pragma unroll
        for (int k = 0; k < 8; k++) {
            a0 += bf_lo(uu[k].x); a1 += bf_hi(uu[k].x);
            a2 += bf_lo(uu[k].y); a3 += bf_hi(uu[k].y);
            a4 += bf_lo(uu[k].z); a5 += bf_hi(uu[k].z);
            a6 += bf_lo(uu[k].w); a7 += bf_hi(uu[k].w);
        }
    }
    float4 b0 = *(const float4*)&bias[8 * sl];
    float4 b1 = *(const float4*)&bias[8 * sl + 4];
    float r0 = fmaxf(di * a0 + b0.x, 0.f);    // ReLU folded (layer-1 epilogue)
    float r1 = fmaxf(di * a1 + b0.y, 0.f);
    float r2 = fmaxf(di * a2 + b0.z, 0.f);
    float r3 = fmaxf(di * a3 + b0.w, 0.f);
    float r4 = fmaxf(di * a4 + b1.x, 0.f);
    float r5 = fmaxf(di * a5 + b1.y, 0.f);
    float r6 = fmaxf(di * a6 + b1.z, 0.f);
    float r7 = fmaxf(di * a7 + b1.w, 0.f);
    uint4 o;
    o.x = (unsigned)f2bf(r0) | ((unsigned)f2bf(r1) << 16);
    o.y = (unsigned)f2bf(r2) | ((unsigned)f2bf(r3) << 16);
    o.z = (unsigned)f2bf(r4) | ((unsigned)f2bf(r5) << 16);
    o.w = (unsigned)f2bf(r6) | ((unsigned)f2bf(r7) << 16);
    *(uint4*)&h1[(size_t)i * 64 + 4 * sl] = o;
}

// Aggregate 64-wide bf16 rows (pre-scaled). 8 nodes/wave: 8 lanes per node,
// uint4 per lane covers cols 8sl..8sl+7 (full 64-col row = 8 lanes x 16B).
// Every lane holds complete sums for its 8 cols -> no partial-sum combine.
// log_softmax fused (reduce over 8-lane group).
__global__ __launch_bounds__(256) void k_agg64b(const unsigned* __restrict__ csr_off,
                                                const int* __restrict__ rowptr,
                                                const int* __restrict__ cnt,
                                                const float* __restrict__ dinv,
                                                const unsigned char* __restrict__ xwb,
                                                const float* __restrict__ bias,
                                                float* __restrict__ out, int N) {
    const int lane = threadIdx.x & 63;
    const int wid = (blockIdx.x * blockDim.x + threadIdx.x) >> 6;
    const int g = lane >> 3, sl = lane & 7;
    const int i = wid * 8 + g;
    if (i >= N) return;
    const float di = dinv[i];
    const int slb = sl * 16;
    uint4 u = *(const uint4*)(xwb + ((size_t)i << 7) + slb);   // self row (128B rows)
    float a0 = bf_lo(u.x), a1 = bf_hi(u.x), a2 = bf_lo(u.y), a3 = bf_hi(u.y);
    float a4 = bf_lo(u.z), a5 = bf_hi(u.z), a6 = bf_lo(u.w), a7 = bf_hi(u.w);
    const int start = rowptr[i];
    const int pc = (cnt[i] + 7) & ~7;
    unsigned s[8];
#pragma unroll
    for (int k = 0; k < 8; k++) s[k] = csr_off[start + k];
    for (int j = 0; j < pc; j += 8) {
        uint4 uu[8];
#pragma unroll
        for (int k = 0; k < 8; k++) uu[k] = *(const uint4*)(xwb + (s[k] >> 1) + slb);
#pragma unroll
        for (int k = 0; k < 8; k++) s[k] = csr_off[start + j + 8 + k];
#pragma unroll
        for (int k = 0; k < 8; k++) {
            a0 += bf_lo(uu[k].x); a1 += bf_hi(uu[k].x);
            a2 += bf_lo(uu[k].y); a3 += bf_hi(uu[k].y);
            a4 += bf_lo(uu[k].z); a5 += bf_hi(uu[k].z);
            a6 += bf_lo(uu[k].w); a7 += bf_hi(uu[k].w);
        }
    }
    float4 b0 = *(const float4*)&bias[8 * sl];
    float4 b1 = *(const float4*)&bias[8 * sl + 4];
    float v0 = di * a0 + b0.x, v1 = di * a1 + b0.y;
    float v2 = di * a2 + b0.z, v3 = di * a3 + b0.w;
    float v4 = di * a4 + b1.x, v5 = di * a5 + b1.y;
    float v6 = di * a6 + b1.z, v7 = di * a7 + b1.w;
    // fused log_softmax over 64 cols (8 per lane x 8-lane group)
    float m = fmaxf(fmaxf(fmaxf(v0, v1), fmaxf(v2, v3)),
                    fmaxf(fmaxf(v4, v5), fmaxf(v6, v7)));
#pragma unroll
    for (int o = 4; o > 0; o >>= 1) m = fmaxf(m, __shfl_xor(m, o));
    float s2 = expf(v0 - m) + expf(v1 - m) + expf(v2 - m) + expf(v3 - m) +
               expf(v4 - m) + expf(v5 - m) + expf(v6 - m) + expf(v7 - m);
#pragma unroll
    for (int o = 4; o > 0; o >>= 1) s2 += __shfl_xor(s2, o);
    float ls = m + logf(s2);
    *(float4*)&out[(size_t)i * 64 + 8 * sl] = make_float4(v0 - ls, v1 - ls, v2 - ls, v3 - ls);
    *(float4*)&out[(size_t)i * 64 + 8 * sl + 4] = make_float4(v4 - ls, v5 - ls, v6 - ls, v7 - ls);
}

extern "C" void kernel_launch(void* const* d_in, const int* in_sizes, int n_in,
                              void* d_out, int out_size, void* d_ws, size_t ws_size,
                              hipStream_t stream) {
    const float* x  = (const float*)d_in[0];
    const int*   ei = (const int*)d_in[1];
    const float* W1 = (const float*)d_in[2];
    const float* b1 = (const float*)d_in[3];
    const float* W2 = (const float*)d_in[4];
    const float* b2 = (const float*)d_in[5];

    const int N = in_sizes[0] / 128;   // 100000
    const int E = in_sizes[1] / 2;     // 1600000
    const int* src = ei;
    const int* dst = ei + E;
    const int B = (N + 255) >> BSHIFT; // 391 buckets

    char* ws = (char*)d_ws;
    size_t off = 0;
    auto alloc = [&](size_t bytes) {
        void* p = ws + off;
        off += (bytes + 255) & ~(size_t)255;
        return p;
    };
    int*            bcnt    = (int*)alloc(MAXB * 4 * 2);    // bcnt + bfill adjacent
    int*            bfill   = bcnt + MAXB;
    int*            boff    = (int*)alloc((MAXB + 1) * 4);
    int*            deg     = (int*)alloc((size_t)N * 4);
    float*          dinv    = (float*)alloc((size_t)N * 4);
    int*            rowptr  = (int*)alloc((size_t)N * 4);
    // padded CSR: per-bucket slack PADSLACK + 64 ints of end slack for prefetch overread
    unsigned*       csr_off = (unsigned*)alloc(((size_t)E + (size_t)B * PADSLACK + 64) * 4);
    unsigned*       pairs   = (unsigned*)alloc((size_t)E * 4);
    unsigned short* Wt1     = (unsigned short*)alloc(128 * 128 * 2);
    unsigned short* Wt2     = (unsigned short*)alloc(64 * 128 * 2);
    unsigned short* xw1     = (unsigned short*)alloc((size_t)(N + 1) * 128 * 2);  // +1: dummy zero row
    unsigned short* h1      = (unsigned short*)alloc((size_t)N * 128 * 2);        // bf16
    unsigned short* hw2     = xw1;     // reused; dummy row N (64-col layout) zeroed by gemm2
    float*          out     = (float*)d_out;

    hipMemsetAsync(bcnt, 0, MAXB * 4 * 2, stream);

    // CSR build (bucketed, XCD-local, padded to x8 per node, byte offsets)
    k_bcount<<<512, THREADS, 0, stream>>>(dst, E, B, bcnt);
    k_bscan<<<1, MAXB, 0, stream>>>(bcnt, B, boff);
    k_bscatter<<<(E + 8191) / 8192, THREADS, 0, stream>>>(src, dst, E, B, boff, bfill, pairs);
    k_bbuild<<<B, THREADS, 0, stream>>>(pairs, boff, N, deg, dinv, rowptr, csr_off);

    k_castW<<<96, THREADS, 0, stream>>>(W1, W2, Wt1, Wt2);

    // agg grids: agg128 = 4 nodes/wave, agg64 = 8 nodes/wave
    const int agg128Blocks = (N + 15) / 16;   // ceil(N/4) waves / 4 waves-per-block
    const int agg64Blocks  = (N + 31) / 32;   // ceil(N/8) waves / 4 waves-per-block

    // Layer 1
    k_gemm_mfma<128, false><<<(N + 63) / 64, THREADS, 0, stream>>>(
        x, Wt1, dinv, xw1, xw1 + (size_t)N * 128, N);
    k_agg128b<<<agg128Blocks, THREADS, 0, stream>>>(
        csr_off, rowptr, deg, dinv, (const unsigned char*)xw1, b1, (unsigned*)h1, N);

    // Layer 2 (+ fused log_softmax); gemm2 zeroes hw2 dummy row (after agg128 consumed xw1)
    k_gemm_mfma<64, true><<<(N + 63) / 64, THREADS, 0, stream>>>(
        h1, Wt2, dinv, hw2, hw2 + (size_t)N * 64, N);
    k_agg64b<<<agg64Blocks, THREADS, 0, stream>>>(
        csr_off, rowptr, deg, dinv, (const unsigned char*)hw2, b2, out, N);
}